// Round 2
// baseline (4343.123 us; speedup 1.0000x reference)
//
#include <hip/hip_runtime.h>
#include <stdint.h>

typedef __attribute__((ext_vector_type(8))) short short8;
typedef __attribute__((ext_vector_type(4))) float f32x4;

#define LDST 72  // LDS row stride in bf16 elems (64 + 8 pad; 144B = 9*16 keeps 16B align)

__device__ __forceinline__ float bf2f(unsigned short u) {
  union { unsigned int i; float f; } v;
  v.i = ((unsigned int)u) << 16;
  return v.f;
}
__device__ __forceinline__ unsigned short f2bf(float f) {
  union { float f; unsigned int i; } v;
  v.f = f;
  unsigned int u = v.i;
  return (unsigned short)((u + 0x7FFFu + ((u >> 16) & 1u)) >> 16);
}

// ---------------------------------------------------------------------------
// Weight transpose + fp32->bf16: WT[n][k] = (k<K1 ? W1[k][n] : W2[k-K1][n])
// ---------------------------------------------------------------------------
__global__ __launch_bounds__(256) void build_wt(
    const float* __restrict__ W1,            // [K1, N] fp32
    const float* __restrict__ W2,            // [256-K1, N] fp32 or nullptr
    unsigned short* __restrict__ WT,         // [N, 256] bf16
    int K1, int N)
{
  int idx = blockIdx.x * 256 + threadIdx.x;
  if (idx >= N * 256) return;
  int n = idx >> 8;
  int k = idx & 255;
  float v = (k < K1) ? W1[(size_t)k * N + n] : W2[(size_t)(k - K1) * N + n];
  WT[idx] = f2bf(v);
}

// ---------------------------------------------------------------------------
// Layer-1 scatter (fp32 features, both directions) + degree count.
// 32 threads per edge, float4 per thread (feature dim 128).
// ---------------------------------------------------------------------------
__global__ __launch_bounds__(256) void scatter1(
    const float* __restrict__ xu,            // [NU,128]
    const float* __restrict__ xi,            // [NI,128]
    const int* __restrict__ esrc,
    const int* __restrict__ edst,
    float* __restrict__ aggI,                // [NI,128]
    float* __restrict__ aggU,                // [NU,128]
    float* __restrict__ degI,
    float* __restrict__ degU,
    int E)
{
  int t = blockIdx.x * 256 + threadIdx.x;
  int e = t >> 5;
  if (e >= E) return;
  int c = (t & 31) << 2;
  int s = esrc[e];
  int d = edst[e];
  float4 vu = *(const float4*)(xu + (size_t)s * 128 + c);
  float4 vi = *(const float4*)(xi + (size_t)d * 128 + c);
  float* pI = aggI + (size_t)d * 128 + c;
  float* pU = aggU + (size_t)s * 128 + c;
  atomicAdd(pI + 0, vu.x); atomicAdd(pI + 1, vu.y);
  atomicAdd(pI + 2, vu.z); atomicAdd(pI + 3, vu.w);
  atomicAdd(pU + 0, vi.x); atomicAdd(pU + 1, vi.y);
  atomicAdd(pU + 2, vi.z); atomicAdd(pU + 3, vi.w);
  if ((t & 31) == 0) {
    atomicAdd(degI + d, 1.0f);
    atomicAdd(degU + s, 1.0f);
  }
}

// ---------------------------------------------------------------------------
// Layer-2 scatter, one direction: agg[sidx[e]] += p[gidx[e]] (p is bf16)
// ---------------------------------------------------------------------------
__global__ __launch_bounds__(256) void scatter_dir(
    const unsigned short* __restrict__ p,    // [*,128] bf16
    const int* __restrict__ gidx,
    const int* __restrict__ sidx,
    float* __restrict__ agg,                 // [*,128] fp32
    int E)
{
  int t = blockIdx.x * 256 + threadIdx.x;
  int e = t >> 5;
  if (e >= E) return;
  int c = (t & 31) << 2;
  int g = gidx[e];
  int s = sidx[e];
  ushort4 v = *(const ushort4*)(p + (size_t)g * 128 + c);
  float* pa = agg + (size_t)s * 128 + c;
  atomicAdd(pa + 0, bf2f(v.x)); atomicAdd(pa + 1, bf2f(v.y));
  atomicAdd(pa + 2, bf2f(v.z)); atomicAdd(pa + 3, bf2f(v.w));
}

// ---------------------------------------------------------------------------
// K=256 MFMA GEMM, 128x128 tile, 4 waves (2x2), 64x64 per wave.
// mode1 (Aagg != null): A rows = [Aagg/deg (fp32, k<128) | Af (fp32, k>=128)]
// mode0: A = Ab, [M,256] bf16.
// Epilogue: +bias, +Cagg[row][col]/max(degC,1) (N==128 only), relu;
// out fp32 or bf16 per outF32.
// ---------------------------------------------------------------------------
__global__ __launch_bounds__(256) void gemm_k256(
    const unsigned short* __restrict__ Ab,
    const float* __restrict__ Af,
    const float* __restrict__ Aagg,
    const float* __restrict__ degA,
    const unsigned short* __restrict__ BT,   // [N,256] bf16
    const float* __restrict__ bias,
    const float* __restrict__ Cagg,
    const float* __restrict__ degC,
    void* __restrict__ outp,
    int outF32, int M, int N, int doRelu)
{
  __shared__ __attribute__((aligned(16))) unsigned short lA[128 * LDST];
  __shared__ __attribute__((aligned(16))) unsigned short lB[128 * LDST];

  const int tid = threadIdx.x;
  const int lane = tid & 63;
  const int wave = tid >> 6;
  const int waveM = wave >> 1;
  const int waveN = wave & 1;
  const int quad = lane >> 4;
  const int r16 = lane & 15;

  const int rowBase = blockIdx.x * 128;
  const int nBase = blockIdx.y * 128;

  f32x4 acc[4][4];
#pragma unroll
  for (int i = 0; i < 4; ++i)
#pragma unroll
    for (int j = 0; j < 4; ++j) acc[i][j] = (f32x4){0.f, 0.f, 0.f, 0.f};

  const bool mode1 = (Aagg != nullptr);

  for (int kb = 0; kb < 4; ++kb) {
    const int kBase = kb * 64;
    if (kb) __syncthreads();

    // ---- stage A tile [128 rows x 64 k] ----
#pragma unroll
    for (int i = 0; i < 4; ++i) {
      int c = tid + i * 256;
      int row = c >> 3;
      int col8 = (c & 7) << 3;
      int grow = rowBase + row;
      uint4 v = make_uint4(0u, 0u, 0u, 0u);
      if (grow < M) {
        if (mode1) {
          const float* src;
          float s;
          if (kb < 2) {
            src = Aagg + (size_t)grow * 128 + kBase + col8;
            s = 1.0f / fmaxf(degA[grow], 1.0f);
          } else {
            src = Af + (size_t)grow * 128 + (kBase - 128) + col8;
            s = 1.0f;
          }
          float4 u0 = *(const float4*)src;
          float4 u1 = *(const float4*)(src + 4);
          v.x = (unsigned int)f2bf(u0.x * s) | ((unsigned int)f2bf(u0.y * s) << 16);
          v.y = (unsigned int)f2bf(u0.z * s) | ((unsigned int)f2bf(u0.w * s) << 16);
          v.z = (unsigned int)f2bf(u1.x * s) | ((unsigned int)f2bf(u1.y * s) << 16);
          v.w = (unsigned int)f2bf(u1.z * s) | ((unsigned int)f2bf(u1.w * s) << 16);
        } else {
          v = *(const uint4*)(Ab + (size_t)grow * 256 + kBase + col8);
        }
      }
      *(uint4*)(lA + row * LDST + col8) = v;
    }
    // ---- stage B tile [128 n x 64 k] ----
#pragma unroll
    for (int i = 0; i < 4; ++i) {
      int c = tid + i * 256;
      int row = c >> 3;
      int col8 = (c & 7) << 3;
      uint4 v = *(const uint4*)(BT + (size_t)(nBase + row) * 256 + kBase + col8);
      *(uint4*)(lB + row * LDST + col8) = v;
    }
    __syncthreads();

    // ---- compute: 2 K-steps of 32 ----
#pragma unroll
    for (int kk = 0; kk < 64; kk += 32) {
      short8 a[4], b[4];
#pragma unroll
      for (int mt = 0; mt < 4; ++mt)
        a[mt] = *(const short8*)(lA + (waveM * 64 + mt * 16 + r16) * LDST + kk + quad * 8);
#pragma unroll
      for (int nt = 0; nt < 4; ++nt)
        b[nt] = *(const short8*)(lB + (waveN * 64 + nt * 16 + r16) * LDST + kk + quad * 8);
#pragma unroll
      for (int mt = 0; mt < 4; ++mt)
#pragma unroll
        for (int nt = 0; nt < 4; ++nt)
          acc[mt][nt] = __builtin_amdgcn_mfma_f32_16x16x32_bf16(a[mt], b[nt], acc[mt][nt], 0, 0, 0);
    }
  }

  // ---- epilogue ----
#pragma unroll
  for (int mt = 0; mt < 4; ++mt) {
#pragma unroll
    for (int nt = 0; nt < 4; ++nt) {
      int col = nBase + waveN * 64 + nt * 16 + r16;
      float bv = bias ? bias[col] : 0.0f;
#pragma unroll
      for (int reg = 0; reg < 4; ++reg) {
        int row = rowBase + waveM * 64 + mt * 16 + quad * 4 + reg;
        if (row < M) {
          float v = acc[mt][nt][reg] + bv;
          if (Cagg) {
            float s = 1.0f / fmaxf(degC[row], 1.0f);
            v += Cagg[(size_t)row * 128 + col] * s;
          }
          if (doRelu) v = fmaxf(v, 0.0f);
          if (outF32) ((float*)outp)[(size_t)row * N + col] = v;
          else ((unsigned short*)outp)[(size_t)row * N + col] = f2bf(v);
        }
      }
    }
  }
}

// ---------------------------------------------------------------------------
extern "C" void kernel_launch(void* const* d_in, const int* in_sizes, int n_in,
                              void* d_out, int out_size, void* d_ws, size_t ws_size,
                              hipStream_t stream)
{
  const float* x_user  = (const float*)d_in[0];
  const float* x_item  = (const float*)d_in[1];
  const int*   esrc    = (const int*)d_in[2];
  const int*   edst    = (const int*)d_in[3];
  const float* W_l1_ui = (const float*)d_in[4];
  const float* W_r1_ui = (const float*)d_in[5];
  const float* b_l1_ui = (const float*)d_in[6];
  const float* W_l1_iu = (const float*)d_in[7];
  const float* W_r1_iu = (const float*)d_in[8];
  const float* b_l1_iu = (const float*)d_in[9];
  const float* W_l2_ui = (const float*)d_in[10];
  const float* W_r2_ui = (const float*)d_in[11];
  const float* b_l2_ui = (const float*)d_in[12];
  const float* W_l2_iu = (const float*)d_in[13];
  const float* W_r2_iu = (const float*)d_in[14];
  const float* b_l2_iu = (const float*)d_in[15];

  const int NU = in_sizes[0] / 128;   // 200000
  const int NI = in_sizes[1] / 128;   // 100000
  const int E  = in_sizes[2];         // 500000

  char* ws = (char*)d_ws;
  size_t off = 0;
  auto alloc = [&](size_t bytes) -> void* {
    void* p = ws + off;
    off += (bytes + 255) & ~(size_t)255;
    return p;
  };

  // Region R (153.6 MB) is time-shared:
  //   layer 1: [aggI fp32 NI*128 | aggU fp32 NU*128]
  //   phase A: [p_user bf16 NU*128 | agg2I fp32 NI*128]
  //   phase B: [p_item bf16 NI*128 | agg2U fp32 NU*128]
  char* R = (char*)alloc((size_t)(NI + NU) * 128 * 4);
  float* degI = (float*)alloc((size_t)NI * 4);
  float* degU = (float*)alloc((size_t)NU * 4);
  size_t zeroBytes = off;              // R + degrees, contiguous from ws[0]
  unsigned short* h_item  = (unsigned short*)alloc((size_t)NI * 256 * 2);
  unsigned short* h_user  = (unsigned short*)alloc((size_t)NU * 256 * 2);
  unsigned short* WT1_ui  = (unsigned short*)alloc(256 * 256 * 2);
  unsigned short* WT1_iu  = (unsigned short*)alloc(256 * 256 * 2);
  unsigned short* WT2l_ui = (unsigned short*)alloc(128 * 256 * 2);
  unsigned short* WT2r_ui = (unsigned short*)alloc(128 * 256 * 2);
  unsigned short* WT2l_iu = (unsigned short*)alloc(128 * 256 * 2);
  unsigned short* WT2r_iu = (unsigned short*)alloc(128 * 256 * 2);

  float* aggI = (float*)R;
  float* aggU = (float*)(R + (size_t)NI * 128 * 4);
  unsigned short* p_user = (unsigned short*)R;
  float* agg2I = (float*)(R + (size_t)NU * 128 * 2);           // = R + 51.2MB
  unsigned short* p_item = (unsigned short*)R;
  float* agg2U = (float*)(R + (size_t)NI * 128 * 2);           // = R + 25.6MB

  float* out = (float*)d_out;          // [o_user (NU*128) | o_item (NI*128)] fp32

  // 1) zero layer-1 accumulators + degrees
  hipMemsetAsync(ws, 0, zeroBytes, stream);

  // 2) weight transposes (fp32 -> bf16)
  build_wt<<<256, 256, 0, stream>>>(W_l1_ui, W_r1_ui, WT1_ui, 128, 256);
  build_wt<<<256, 256, 0, stream>>>(W_l1_iu, W_r1_iu, WT1_iu, 128, 256);
  build_wt<<<128, 256, 0, stream>>>(W_l2_ui, nullptr, WT2l_ui, 256, 128);
  build_wt<<<128, 256, 0, stream>>>(W_r2_ui, nullptr, WT2r_ui, 256, 128);
  build_wt<<<128, 256, 0, stream>>>(W_l2_iu, nullptr, WT2l_iu, 256, 128);
  build_wt<<<128, 256, 0, stream>>>(W_r2_iu, nullptr, WT2r_iu, 256, 128);

  // 3) layer-1 scatter + degrees
  int sgrid = (E * 32 + 255) / 256;
  scatter1<<<sgrid, 256, 0, stream>>>(x_user, x_item, esrc, edst,
                                      aggI, aggU, degI, degU, E);

  // 4) layer-1 GEMMs: h = relu([mean | x] @ [W_l; W_r] + b), bf16 out
  dim3 gI((NI + 127) / 128, 2), gU((NU + 127) / 128, 2);
  gemm_k256<<<gI, 256, 0, stream>>>(nullptr, x_item, aggI, degI, WT1_ui, b_l1_ui,
                                    nullptr, nullptr, h_item, 0, NI, 256, 1);
  gemm_k256<<<gU, 256, 0, stream>>>(nullptr, x_user, aggU, degU, WT1_iu, b_l1_iu,
                                    nullptr, nullptr, h_user, 0, NU, 256, 1);

  dim3 pGu((NU + 127) / 128, 1), pGi((NI + 127) / 128, 1);

  // ---- phase A: o_item ----
  // p_user = h_user @ W_l2_ui (bf16, no relu/bias)
  gemm_k256<<<pGu, 256, 0, stream>>>(h_user, nullptr, nullptr, nullptr, WT2l_ui,
                                     nullptr, nullptr, nullptr, p_user, 0, NU, 128, 0);
  hipMemsetAsync(agg2I, 0, (size_t)NI * 128 * 4, stream);
  scatter_dir<<<sgrid, 256, 0, stream>>>(p_user, esrc, edst, agg2I, E);
  gemm_k256<<<pGi, 256, 0, stream>>>(h_item, nullptr, nullptr, nullptr, WT2r_ui,
                                     b_l2_ui, agg2I, degI,
                                     out + (size_t)NU * 128, 1, NI, 128, 1);

  // ---- phase B: o_user ----
  gemm_k256<<<pGi, 256, 0, stream>>>(h_item, nullptr, nullptr, nullptr, WT2l_iu,
                                     nullptr, nullptr, nullptr, p_item, 0, NI, 128, 0);
  hipMemsetAsync(agg2U, 0, (size_t)NU * 128 * 4, stream);
  scatter_dir<<<sgrid, 256, 0, stream>>>(p_item, edst, esrc, agg2U, E);
  gemm_k256<<<pGu, 256, 0, stream>>>(h_user, nullptr, nullptr, nullptr, WT2r_iu,
                                     b_l2_iu, agg2U, degU,
                                     out, 1, NU, 128, 1);
}

// Round 3
// 1582.654 us; speedup vs baseline: 2.7442x; 2.7442x over previous
//
#include <hip/hip_runtime.h>
#include <stdint.h>

typedef __attribute__((ext_vector_type(8))) short short8;
typedef __attribute__((ext_vector_type(4))) float f32x4;

#define LDST 72  // LDS row stride in bf16 elems (64 + 8 pad; 144B = 9*16 keeps 16B align)

__device__ __forceinline__ float bf2f(unsigned short u) {
  union { unsigned int i; float f; } v;
  v.i = ((unsigned int)u) << 16;
  return v.f;
}
__device__ __forceinline__ unsigned short f2bf(float f) {
  union { float f; unsigned int i; } v;
  v.f = f;
  unsigned int u = v.i;
  return (unsigned short)((u + 0x7FFFu + ((u >> 16) & 1u)) >> 16);
}
__device__ __forceinline__ unsigned int pack2(float a, float b) {
  return (unsigned int)f2bf(a) | ((unsigned int)f2bf(b) << 16);
}

// ---------------------------------------------------------------------------
// Weight transpose + fp32->bf16: WT[n][k] = (k<K1 ? W1[k][n] : W2[k-K1][n])
// ---------------------------------------------------------------------------
__global__ __launch_bounds__(256) void build_wt(
    const float* __restrict__ W1, const float* __restrict__ W2,
    unsigned short* __restrict__ WT, int K1, int N)
{
  int idx = blockIdx.x * 256 + threadIdx.x;
  if (idx >= N * 256) return;
  int n = idx >> 8;
  int k = idx & 255;
  float v = (k < K1) ? W1[(size_t)k * N + n] : W2[(size_t)(k - K1) * N + n];
  WT[idx] = f2bf(v);
}

// ---------------------------------------------------------------------------
// CSR build: histogram -> exclusive scan -> fill gather-index lists
// ---------------------------------------------------------------------------
__global__ __launch_bounds__(256) void hist(
    const int* __restrict__ esrc, const int* __restrict__ edst,
    int* __restrict__ cntU, int* __restrict__ cntI, int E)
{
  int e = blockIdx.x * 256 + threadIdx.x;
  if (e >= E) return;
  atomicAdd(&cntI[edst[e]], 1);
  atomicAdd(&cntU[esrc[e]], 1);
}

// one block per array (blockIdx.x: 0=item,1=user); 1024 threads, chunked scan
__global__ __launch_bounds__(1024) void scan_two(
    const int* __restrict__ cntA, int* __restrict__ offA, int NA,
    const int* __restrict__ cntB, int* __restrict__ offB, int NB)
{
  const int* cnt = blockIdx.x ? cntB : cntA;
  int* off = blockIdx.x ? offB : offA;
  int N = blockIdx.x ? NB : NA;
  __shared__ int lsum[1024];
  int t = threadIdx.x;
  int chunk = (N + 1023) >> 10;
  int lo = t * chunk;
  int hi = min(lo + chunk, N);
  int s = 0;
  for (int i = lo; i < hi; ++i) s += cnt[i];
  lsum[t] = s;
  __syncthreads();
  for (int d = 1; d < 1024; d <<= 1) {
    int v = (t >= d) ? lsum[t - d] : 0;
    __syncthreads();
    lsum[t] += v;
    __syncthreads();
  }
  int run = (t == 0) ? 0 : lsum[t - 1];   // exclusive prefix of this chunk
  for (int i = lo; i < hi; ++i) { off[i] = run; run += cnt[i]; }
  if (t == 1023) off[N] = lsum[1023];     // grand total
}

__global__ __launch_bounds__(256) void fill_idx(
    const int* __restrict__ esrc, const int* __restrict__ edst,
    const int* __restrict__ offU, const int* __restrict__ offI,
    int* __restrict__ curU, int* __restrict__ curI,
    int* __restrict__ idxU, int* __restrict__ idxI, int E)
{
  int e = blockIdx.x * 256 + threadIdx.x;
  if (e >= E) return;
  int s = esrc[e], d = edst[e];
  int pI = offI[d] + atomicAdd(&curI[d], 1);
  idxI[pI] = s;                           // item n aggregates x_user[idxI[...]]
  int pU = offU[s] + atomicAdd(&curU[s], 1);
  idxU[pU] = d;                           // user n aggregates x_item[idxU[...]]
}

// ---------------------------------------------------------------------------
// Layer-1 aggregation: one wave per node. Emits Acat[n] = [mean | x_self] bf16.
// ---------------------------------------------------------------------------
__global__ __launch_bounds__(256) void build_acat(
    const float* __restrict__ x_other,   // gathered rows [*,128] fp32
    const float* __restrict__ x_self,    // [N,128] fp32
    const int* __restrict__ idx, const int* __restrict__ off,
    unsigned int* __restrict__ Acat,     // [N,128] uints = [N,256] bf16
    int N)
{
  int w = (blockIdx.x * 256 + threadIdx.x) >> 6;
  if (w >= N) return;
  int l = threadIdx.x & 63;
  int s = off[w], e = off[w + 1];
  float ax = 0.f, ay = 0.f;
  for (int j = s; j < e; ++j) {
    int g = idx[j];
    float2 v = *(const float2*)(x_other + (size_t)g * 128 + l * 2);
    ax += v.x; ay += v.y;
  }
  float inv = 1.0f / (float)max(e - s, 1);
  float2 xv = *(const float2*)(x_self + (size_t)w * 128 + l * 2);
  Acat[(size_t)w * 128 + l]      = pack2(ax * inv, ay * inv);
  Acat[(size_t)w * 128 + 64 + l] = pack2(xv.x, xv.y);
}

// ---------------------------------------------------------------------------
// Layer-2 aggregation: one wave per node, gather bf16 p-rows, write bf16 mean.
// ---------------------------------------------------------------------------
__global__ __launch_bounds__(256) void seg_mean_bf(
    const unsigned int* __restrict__ p,  // [*,64] uint = [*,128] bf16
    const int* __restrict__ idx, const int* __restrict__ off,
    unsigned int* __restrict__ m2,       // [N,64] uint = [N,128] bf16
    int N)
{
  int w = (blockIdx.x * 256 + threadIdx.x) >> 6;
  if (w >= N) return;
  int l = threadIdx.x & 63;
  int s = off[w], e = off[w + 1];
  float ax = 0.f, ay = 0.f;
  for (int j = s; j < e; ++j) {
    int g = idx[j];
    unsigned int v = p[(size_t)g * 64 + l];
    ax += bf2f((unsigned short)(v & 0xffff));
    ay += bf2f((unsigned short)(v >> 16));
  }
  float inv = 1.0f / (float)max(e - s, 1);
  m2[(size_t)w * 64 + l] = pack2(ax * inv, ay * inv);
}

// ---------------------------------------------------------------------------
// K=256 MFMA GEMM, 128x128 tile, 4 waves (2x2), 64x64 per wave.
// A = [M,256] bf16. Epilogue: +bias, +Madd (bf16 [M,128], N==128 calls only),
// relu; out fp32 or bf16.
// ---------------------------------------------------------------------------
__global__ __launch_bounds__(256) void gemm_k256(
    const unsigned short* __restrict__ A,    // [M,256] bf16
    const unsigned short* __restrict__ BT,   // [N,256] bf16
    const float* __restrict__ bias,
    const unsigned short* __restrict__ Madd, // [M,128] bf16 or null
    void* __restrict__ outp,
    int outF32, int M, int N, int doRelu)
{
  __shared__ __attribute__((aligned(16))) unsigned short lA[128 * LDST];
  __shared__ __attribute__((aligned(16))) unsigned short lB[128 * LDST];

  const int tid = threadIdx.x;
  const int lane = tid & 63;
  const int wave = tid >> 6;
  const int waveM = wave >> 1;
  const int waveN = wave & 1;
  const int quad = lane >> 4;
  const int r16 = lane & 15;

  const int rowBase = blockIdx.x * 128;
  const int nBase = blockIdx.y * 128;

  f32x4 acc[4][4];
#pragma unroll
  for (int i = 0; i < 4; ++i)
#pragma unroll
    for (int j = 0; j < 4; ++j) acc[i][j] = (f32x4){0.f, 0.f, 0.f, 0.f};

  for (int kb = 0; kb < 4; ++kb) {
    const int kBase = kb * 64;
    if (kb) __syncthreads();

#pragma unroll
    for (int i = 0; i < 4; ++i) {
      int c = tid + i * 256;
      int row = c >> 3;
      int col8 = (c & 7) << 3;
      int grow = rowBase + row;
      uint4 v = make_uint4(0u, 0u, 0u, 0u);
      if (grow < M) v = *(const uint4*)(A + (size_t)grow * 256 + kBase + col8);
      *(uint4*)(lA + row * LDST + col8) = v;
    }
#pragma unroll
    for (int i = 0; i < 4; ++i) {
      int c = tid + i * 256;
      int row = c >> 3;
      int col8 = (c & 7) << 3;
      uint4 v = *(const uint4*)(BT + (size_t)(nBase + row) * 256 + kBase + col8);
      *(uint4*)(lB + row * LDST + col8) = v;
    }
    __syncthreads();

#pragma unroll
    for (int kk = 0; kk < 64; kk += 32) {
      short8 a[4], b[4];
#pragma unroll
      for (int mt = 0; mt < 4; ++mt)
        a[mt] = *(const short8*)(lA + (waveM * 64 + mt * 16 + r16) * LDST + kk + quad * 8);
#pragma unroll
      for (int nt = 0; nt < 4; ++nt)
        b[nt] = *(const short8*)(lB + (waveN * 64 + nt * 16 + r16) * LDST + kk + quad * 8);
#pragma unroll
      for (int mt = 0; mt < 4; ++mt)
#pragma unroll
        for (int nt = 0; nt < 4; ++nt)
          acc[mt][nt] = __builtin_amdgcn_mfma_f32_16x16x32_bf16(a[mt], b[nt], acc[mt][nt], 0, 0, 0);
    }
  }

#pragma unroll
  for (int mt = 0; mt < 4; ++mt) {
#pragma unroll
    for (int nt = 0; nt < 4; ++nt) {
      int col = nBase + waveN * 64 + nt * 16 + r16;
      float bv = bias ? bias[col] : 0.0f;
#pragma unroll
      for (int reg = 0; reg < 4; ++reg) {
        int row = rowBase + waveM * 64 + mt * 16 + quad * 4 + reg;
        if (row < M) {
          float v = acc[mt][nt][reg] + bv;
          if (Madd) v += bf2f(Madd[(size_t)row * 128 + col]);
          if (doRelu) v = fmaxf(v, 0.0f);
          if (outF32) ((float*)outp)[(size_t)row * N + col] = v;
          else ((unsigned short*)outp)[(size_t)row * N + col] = f2bf(v);
        }
      }
    }
  }
}

// ---------------------------------------------------------------------------
extern "C" void kernel_launch(void* const* d_in, const int* in_sizes, int n_in,
                              void* d_out, int out_size, void* d_ws, size_t ws_size,
                              hipStream_t stream)
{
  const float* x_user  = (const float*)d_in[0];
  const float* x_item  = (const float*)d_in[1];
  const int*   esrc    = (const int*)d_in[2];
  const int*   edst    = (const int*)d_in[3];
  const float* W_l1_ui = (const float*)d_in[4];
  const float* W_r1_ui = (const float*)d_in[5];
  const float* b_l1_ui = (const float*)d_in[6];
  const float* W_l1_iu = (const float*)d_in[7];
  const float* W_r1_iu = (const float*)d_in[8];
  const float* b_l1_iu = (const float*)d_in[9];
  const float* W_l2_ui = (const float*)d_in[10];
  const float* W_r2_ui = (const float*)d_in[11];
  const float* b_l2_ui = (const float*)d_in[12];
  const float* W_l2_iu = (const float*)d_in[13];
  const float* W_r2_iu = (const float*)d_in[14];
  const float* b_l2_iu = (const float*)d_in[15];

  const int NU = in_sizes[0] / 128;   // 200000
  const int NI = in_sizes[1] / 128;   // 100000
  const int E  = in_sizes[2];         // 500000

  char* ws = (char*)d_ws;
  size_t off = 0;
  auto alloc = [&](size_t bytes) -> void* {
    void* p = ws + off;
    off += (bytes + 255) & ~(size_t)255;
    return p;
  };

  // --- zeroed-every-launch region (counts + fill cursors) ---
  int* cntI = (int*)alloc((size_t)NI * 4);
  int* cntU = (int*)alloc((size_t)NU * 4);
  int* curI = (int*)alloc((size_t)NI * 4);
  int* curU = (int*)alloc((size_t)NU * 4);
  size_t zeroBytes = off;
  // --- CSR ---
  int* offI = (int*)alloc((size_t)(NI + 1) * 4);
  int* offU = (int*)alloc((size_t)(NU + 1) * 4);
  int* idxI = (int*)alloc((size_t)E * 4);
  int* idxU = (int*)alloc((size_t)E * 4);
  // --- weights (bf16, transposed) ---
  unsigned short* WT1_ui  = (unsigned short*)alloc(256 * 256 * 2);
  unsigned short* WT1_iu  = (unsigned short*)alloc(256 * 256 * 2);
  unsigned short* WT2l_ui = (unsigned short*)alloc(128 * 256 * 2);
  unsigned short* WT2r_ui = (unsigned short*)alloc(128 * 256 * 2);
  unsigned short* WT2l_iu = (unsigned short*)alloc(128 * 256 * 2);
  unsigned short* WT2r_iu = (unsigned short*)alloc(128 * 256 * 2);
  // --- hidden states (persistent across layer 2) ---
  unsigned short* h_item = (unsigned short*)alloc((size_t)NI * 256 * 2);
  unsigned short* h_user = (unsigned short*)alloc((size_t)NU * 256 * 2);
  // --- time-shared region R (153.6 MB) ---
  char* R = (char*)alloc((size_t)(NI + NU) * 256 * 2);
  // layer-1 phase:
  unsigned int* Acat_item = (unsigned int*)R;                                   // NI*128 uint
  unsigned int* Acat_user = (unsigned int*)(R + (size_t)NI * 256 * 2);          // NU*128 uint
  // layer-2 phase (Acat dead after L1 GEMMs):
  unsigned short* p_user = (unsigned short*)R;                                  // NU*128 bf16
  unsigned short* p_item = (unsigned short*)(R + (size_t)NU * 128 * 2);         // NI*128 bf16
  unsigned short* m2I    = (unsigned short*)(R + (size_t)(NU + NI) * 128 * 2);  // NI*128 bf16
  unsigned short* m2U    = (unsigned short*)(R + (size_t)(NU + 2 * NI) * 128 * 2); // NU*128 bf16

  float* out = (float*)d_out;          // [o_user (NU*128) | o_item (NI*128)] fp32

  // 1) zero counts/cursors
  hipMemsetAsync(ws, 0, zeroBytes, stream);

  // 2) weight transposes (fp32 -> bf16)
  build_wt<<<256, 256, 0, stream>>>(W_l1_ui, W_r1_ui, WT1_ui, 128, 256);
  build_wt<<<256, 256, 0, stream>>>(W_l1_iu, W_r1_iu, WT1_iu, 128, 256);
  build_wt<<<128, 256, 0, stream>>>(W_l2_ui, nullptr, WT2l_ui, 256, 128);
  build_wt<<<128, 256, 0, stream>>>(W_r2_ui, nullptr, WT2r_ui, 256, 128);
  build_wt<<<128, 256, 0, stream>>>(W_l2_iu, nullptr, WT2l_iu, 256, 128);
  build_wt<<<128, 256, 0, stream>>>(W_r2_iu, nullptr, WT2r_iu, 256, 128);

  // 3) CSR build
  int egrid = (E + 255) / 256;
  hist<<<egrid, 256, 0, stream>>>(esrc, edst, cntU, cntI, E);
  scan_two<<<2, 1024, 0, stream>>>(cntI, offI, NI, cntU, offU, NU);
  fill_idx<<<egrid, 256, 0, stream>>>(esrc, edst, offU, offI, curU, curI,
                                      idxU, idxI, E);

  // 4) layer-1 aggregation -> Acat = [mean | x] bf16
  build_acat<<<(NI * 64 + 255) / 256, 256, 0, stream>>>(x_user, x_item, idxI, offI, Acat_item, NI);
  build_acat<<<(NU * 64 + 255) / 256, 256, 0, stream>>>(x_item, x_user, idxU, offU, Acat_user, NU);

  // 5) layer-1 GEMMs: h = relu(Acat @ [W_l; W_r] + b), bf16 out
  dim3 gI((NI + 127) / 128, 2), gU((NU + 127) / 128, 2);
  gemm_k256<<<gI, 256, 0, stream>>>((const unsigned short*)Acat_item, WT1_ui, b_l1_ui,
                                    nullptr, h_item, 0, NI, 256, 1);
  gemm_k256<<<gU, 256, 0, stream>>>((const unsigned short*)Acat_user, WT1_iu, b_l1_iu,
                                    nullptr, h_user, 0, NU, 256, 1);

  // 6) layer-2 left-projections (before aggregation): p = h @ W_l2, bf16
  dim3 pGu((NU + 127) / 128, 1), pGi((NI + 127) / 128, 1);
  gemm_k256<<<pGu, 256, 0, stream>>>(h_user, WT2l_ui, nullptr, nullptr, p_user, 0, NU, 128, 0);
  gemm_k256<<<pGi, 256, 0, stream>>>(h_item, WT2l_iu, nullptr, nullptr, p_item, 0, NI, 128, 0);

  // 7) layer-2 aggregation: m2 = mean of projected neighbor rows
  seg_mean_bf<<<(NI * 64 + 255) / 256, 256, 0, stream>>>((const unsigned int*)p_user, idxI, offI,
                                                         (unsigned int*)m2I, NI);
  seg_mean_bf<<<(NU * 64 + 255) / 256, 256, 0, stream>>>((const unsigned int*)p_item, idxU, offU,
                                                         (unsigned int*)m2U, NU);

  // 8) output GEMMs: o = relu(h @ W_r2 + m2 + b), fp32 out
  gemm_k256<<<pGi, 256, 0, stream>>>(h_item, WT2r_ui, b_l2_ui, m2I,
                                     out + (size_t)NU * 128, 1, NI, 128, 1);
  gemm_k256<<<pGu, 256, 0, stream>>>(h_user, WT2r_iu, b_l2_iu, m2U,
                                     out, 1, NU, 128, 1);
}

// Round 4
// 1268.582 us; speedup vs baseline: 3.4236x; 1.2476x over previous
//
#include <hip/hip_runtime.h>
#include <stdint.h>

typedef __attribute__((ext_vector_type(8))) short short8;
typedef __attribute__((ext_vector_type(4))) float f32x4;

#define LDST 72       // LDS row stride in bf16 elems (64 + 8 pad; 144B keeps 16B align)
#define SCAN_TILE 4096

__device__ __forceinline__ float bf2f(unsigned short u) {
  union { unsigned int i; float f; } v;
  v.i = ((unsigned int)u) << 16;
  return v.f;
}
__device__ __forceinline__ unsigned short f2bf(float f) {
  union { float f; unsigned int i; } v;
  v.f = f;
  unsigned int u = v.i;
  return (unsigned short)((u + 0x7FFFu + ((u >> 16) & 1u)) >> 16);
}
__device__ __forceinline__ unsigned int pack2(float a, float b) {
  return (unsigned int)f2bf(a) | ((unsigned int)f2bf(b) << 16);
}

// ---------------------------------------------------------------------------
// All six weight transposes (fp32 -> bf16, [K,N] -> [N,K-concat]) in one launch.
// Ranges are multiples of 256 so each block is range-uniform.
// ---------------------------------------------------------------------------
__global__ __launch_bounds__(256) void build_wt_all(
    const float* __restrict__ Wl1ui, const float* __restrict__ Wr1ui,
    const float* __restrict__ Wl1iu, const float* __restrict__ Wr1iu,
    const float* __restrict__ Wl2ui, const float* __restrict__ Wr2ui,
    const float* __restrict__ Wl2iu, const float* __restrict__ Wr2iu,
    unsigned short* __restrict__ WT1ui, unsigned short* __restrict__ WT1iu,
    unsigned short* __restrict__ WT2lui, unsigned short* __restrict__ WT2rui,
    unsigned short* __restrict__ WT2liu, unsigned short* __restrict__ WT2riu)
{
  int idx = blockIdx.x * 256 + threadIdx.x;
  const float *W1, *W2 = nullptr;
  unsigned short* WT;
  int K1, N, rel;
  if (idx < 65536)       { W1 = Wl1ui; W2 = Wr1ui; WT = WT1ui;  K1 = 128; N = 256; rel = idx; }
  else if (idx < 131072) { W1 = Wl1iu; W2 = Wr1iu; WT = WT1iu;  K1 = 128; N = 256; rel = idx - 65536; }
  else if (idx < 163840) { W1 = Wl2ui;             WT = WT2lui; K1 = 256; N = 128; rel = idx - 131072; }
  else if (idx < 196608) { W1 = Wr2ui;             WT = WT2rui; K1 = 256; N = 128; rel = idx - 163840; }
  else if (idx < 229376) { W1 = Wl2iu;             WT = WT2liu; K1 = 256; N = 128; rel = idx - 196608; }
  else                   { W1 = Wr2iu;             WT = WT2riu; K1 = 256; N = 128; rel = idx - 229376; }
  int n = rel >> 8;
  int k = rel & 255;
  float v = (k < K1) ? W1[(size_t)k * N + n] : W2[(size_t)(k - K1) * N + n];
  WT[rel] = f2bf(v);
}

// ---------------------------------------------------------------------------
// CSR build over COMBINED node space (items [0,NI), users [NI,NI+NU)).
// Sum of item counts == E, so one exclusive scan gives item offsets in [0,E)
// and user offsets in [E,2E) indexing one shared idxAll[2E].
// ---------------------------------------------------------------------------
__global__ __launch_bounds__(256) void hist(
    const int* __restrict__ esrc, const int* __restrict__ edst,
    int* __restrict__ cntAll, int NI, int E)
{
  int e = blockIdx.x * 256 + threadIdx.x;
  if (e >= E) return;
  atomicAdd(&cntAll[edst[e]], 1);
  atomicAdd(&cntAll[NI + esrc[e]], 1);
}

__global__ __launch_bounds__(256) void scan_p1(
    const int* __restrict__ cnt, int* __restrict__ tileSums, int NA)
{
  __shared__ int red[256];
  int b = blockIdx.x, t = threadIdx.x;
  int base = b * SCAN_TILE;
  int s = 0;
  for (int i = t; i < SCAN_TILE; i += 256) {
    int g = base + i;
    if (g < NA) s += cnt[g];
  }
  red[t] = s;
  __syncthreads();
  for (int d = 128; d > 0; d >>= 1) {
    if (t < d) red[t] += red[t + d];
    __syncthreads();
  }
  if (t == 0) tileSums[b] = red[0];
}

__global__ __launch_bounds__(256) void scan_p2(
    int* __restrict__ tileSums, int nTiles, int* __restrict__ offEnd)
{
  __shared__ int buf[256];
  int t = threadIdx.x;
  int v = (t < nTiles) ? tileSums[t] : 0;
  buf[t] = v;
  __syncthreads();
  for (int d = 1; d < 256; d <<= 1) {
    int x = (t >= d) ? buf[t - d] : 0;
    __syncthreads();
    buf[t] += x;
    __syncthreads();
  }
  if (t < nTiles) tileSums[t] = buf[t] - v;   // exclusive
  if (t == nTiles - 1) *offEnd = buf[t];      // grand total -> offAll[NA]
}

__global__ __launch_bounds__(256) void scan_p3(
    const int* __restrict__ cnt, const int* __restrict__ tileSums,
    int* __restrict__ off, int NA)
{
  __shared__ int red[256];
  int b = blockIdx.x, t = threadIdx.x;
  int base = b * SCAN_TILE + t * 16;
  int loc[16];
  int s = 0;
#pragma unroll
  for (int i = 0; i < 16; ++i) {
    int g = base + i;
    loc[i] = (g < NA) ? cnt[g] : 0;
    s += loc[i];
  }
  red[t] = s;
  __syncthreads();
  for (int d = 1; d < 256; d <<= 1) {
    int x = (t >= d) ? red[t - d] : 0;
    __syncthreads();
    red[t] += x;
    __syncthreads();
  }
  int run = tileSums[b] + red[t] - s;  // exclusive base for this thread
#pragma unroll
  for (int i = 0; i < 16; ++i) {
    int g = base + i;
    if (g < NA) off[g] = run;
    run += loc[i];
  }
}

__global__ __launch_bounds__(256) void fill_idx(
    const int* __restrict__ esrc, const int* __restrict__ edst,
    const int* __restrict__ offAll, int* __restrict__ curAll,
    int* __restrict__ idxAll, int NI, int E)
{
  int e = blockIdx.x * 256 + threadIdx.x;
  if (e >= E) return;
  int s = esrc[e], d = edst[e];
  int pI = offAll[d] + atomicAdd(&curAll[d], 1);
  idxAll[pI] = s;                     // item d aggregates user rows
  int pU = offAll[NI + s] + atomicAdd(&curAll[NI + s], 1);
  idxAll[pU] = d;                     // user s aggregates item rows
}

// ---------------------------------------------------------------------------
// Layer-1 aggregation, both node types in one launch. One wave per node.
// Emits Acat[n] = [mean_neighbors | x_self] bf16 ([*,256]).
// ---------------------------------------------------------------------------
__global__ __launch_bounds__(256) void build_acat(
    const float* __restrict__ xu, const float* __restrict__ xi,
    const int* __restrict__ idxAll, const int* __restrict__ offAll,
    unsigned int* __restrict__ AcatI, unsigned int* __restrict__ AcatU,
    int NI, int NA)
{
  int w = (blockIdx.x * 256 + threadIdx.x) >> 6;
  if (w >= NA) return;
  int l = threadIdx.x & 63;
  bool isItem = (w < NI);
  const float* xo = isItem ? xu : xi;      // neighbor features
  const float* xs = isItem ? xi : xu;      // self features
  unsigned int* Acat = isItem ? AcatI : AcatU;
  int n = isItem ? w : (w - NI);
  int s = offAll[w], e = offAll[w + 1];
  float ax = 0.f, ay = 0.f;
  for (int j = s; j < e; ++j) {
    int g = idxAll[j];
    float2 v = *(const float2*)(xo + (size_t)g * 128 + l * 2);
    ax += v.x; ay += v.y;
  }
  float inv = 1.0f / (float)max(e - s, 1);
  float2 xv = *(const float2*)(xs + (size_t)n * 128 + l * 2);
  Acat[(size_t)n * 128 + l]      = pack2(ax * inv, ay * inv);
  Acat[(size_t)n * 128 + 64 + l] = pack2(xv.x, xv.y);
}

// ---------------------------------------------------------------------------
// Layer-2 aggregation, both node types in one launch. One wave per node.
// m2[n] = mean of projected neighbor rows (bf16 in, bf16 out).
// ---------------------------------------------------------------------------
__global__ __launch_bounds__(256) void seg_mean(
    const unsigned int* __restrict__ pU, const unsigned int* __restrict__ pI,
    const int* __restrict__ idxAll, const int* __restrict__ offAll,
    unsigned int* __restrict__ m2I, unsigned int* __restrict__ m2U,
    int NI, int NA)
{
  int w = (blockIdx.x * 256 + threadIdx.x) >> 6;
  if (w >= NA) return;
  int l = threadIdx.x & 63;
  bool isItem = (w < NI);
  const unsigned int* p = isItem ? pU : pI;
  unsigned int* m2 = isItem ? m2I : m2U;
  int n = isItem ? w : (w - NI);
  int s = offAll[w], e = offAll[w + 1];
  float ax = 0.f, ay = 0.f;
  for (int j = s; j < e; ++j) {
    int g = idxAll[j];
    unsigned int v = p[(size_t)g * 64 + l];
    ax += bf2f((unsigned short)(v & 0xffff));
    ay += bf2f((unsigned short)(v >> 16));
  }
  float inv = 1.0f / (float)max(e - s, 1);
  m2[(size_t)n * 64 + l] = pack2(ax * inv, ay * inv);
}

// ---------------------------------------------------------------------------
// K=256 MFMA GEMM, 128x128 tile, 4 waves (2x2), 64x64 per wave.
// A = [M,256] bf16. Epilogue: +bias, +Madd (bf16 [M,128], N==128 calls only),
// relu; out fp32 or bf16.
// ---------------------------------------------------------------------------
__global__ __launch_bounds__(256) void gemm_k256(
    const unsigned short* __restrict__ A,    // [M,256] bf16
    const unsigned short* __restrict__ BT,   // [N,256] bf16
    const float* __restrict__ bias,
    const unsigned short* __restrict__ Madd, // [M,128] bf16 or null
    void* __restrict__ outp,
    int outF32, int M, int N, int doRelu)
{
  __shared__ __attribute__((aligned(16))) unsigned short lA[128 * LDST];
  __shared__ __attribute__((aligned(16))) unsigned short lB[128 * LDST];

  const int tid = threadIdx.x;
  const int lane = tid & 63;
  const int wave = tid >> 6;
  const int waveM = wave >> 1;
  const int waveN = wave & 1;
  const int quad = lane >> 4;
  const int r16 = lane & 15;

  const int rowBase = blockIdx.x * 128;
  const int nBase = blockIdx.y * 128;

  f32x4 acc[4][4];
#pragma unroll
  for (int i = 0; i < 4; ++i)
#pragma unroll
    for (int j = 0; j < 4; ++j) acc[i][j] = (f32x4){0.f, 0.f, 0.f, 0.f};

  for (int kb = 0; kb < 4; ++kb) {
    const int kBase = kb * 64;
    if (kb) __syncthreads();

#pragma unroll
    for (int i = 0; i < 4; ++i) {
      int c = tid + i * 256;
      int row = c >> 3;
      int col8 = (c & 7) << 3;
      int grow = rowBase + row;
      uint4 v = make_uint4(0u, 0u, 0u, 0u);
      if (grow < M) v = *(const uint4*)(A + (size_t)grow * 256 + kBase + col8);
      *(uint4*)(lA + row * LDST + col8) = v;
    }
#pragma unroll
    for (int i = 0; i < 4; ++i) {
      int c = tid + i * 256;
      int row = c >> 3;
      int col8 = (c & 7) << 3;
      uint4 v = *(const uint4*)(BT + (size_t)(nBase + row) * 256 + kBase + col8);
      *(uint4*)(lB + row * LDST + col8) = v;
    }
    __syncthreads();

#pragma unroll
    for (int kk = 0; kk < 64; kk += 32) {
      short8 a[4], b[4];
#pragma unroll
      for (int mt = 0; mt < 4; ++mt)
        a[mt] = *(const short8*)(lA + (waveM * 64 + mt * 16 + r16) * LDST + kk + quad * 8);
#pragma unroll
      for (int nt = 0; nt < 4; ++nt)
        b[nt] = *(const short8*)(lB + (waveN * 64 + nt * 16 + r16) * LDST + kk + quad * 8);
#pragma unroll
      for (int mt = 0; mt < 4; ++mt)
#pragma unroll
        for (int nt = 0; nt < 4; ++nt)
          acc[mt][nt] = __builtin_amdgcn_mfma_f32_16x16x32_bf16(a[mt], b[nt], acc[mt][nt], 0, 0, 0);
    }
  }

#pragma unroll
  for (int mt = 0; mt < 4; ++mt) {
#pragma unroll
    for (int nt = 0; nt < 4; ++nt) {
      int col = nBase + waveN * 64 + nt * 16 + r16;
      float bv = bias ? bias[col] : 0.0f;
#pragma unroll
      for (int reg = 0; reg < 4; ++reg) {
        int row = rowBase + waveM * 64 + mt * 16 + quad * 4 + reg;
        if (row < M) {
          float v = acc[mt][nt][reg] + bv;
          if (Madd) v += bf2f(Madd[(size_t)row * 128 + col]);
          if (doRelu) v = fmaxf(v, 0.0f);
          if (outF32) ((float*)outp)[(size_t)row * N + col] = v;
          else ((unsigned short*)outp)[(size_t)row * N + col] = f2bf(v);
        }
      }
    }
  }
}

// ---------------------------------------------------------------------------
extern "C" void kernel_launch(void* const* d_in, const int* in_sizes, int n_in,
                              void* d_out, int out_size, void* d_ws, size_t ws_size,
                              hipStream_t stream)
{
  const float* x_user  = (const float*)d_in[0];
  const float* x_item  = (const float*)d_in[1];
  const int*   esrc    = (const int*)d_in[2];
  const int*   edst    = (const int*)d_in[3];
  const float* W_l1_ui = (const float*)d_in[4];
  const float* W_r1_ui = (const float*)d_in[5];
  const float* b_l1_ui = (const float*)d_in[6];
  const float* W_l1_iu = (const float*)d_in[7];
  const float* W_r1_iu = (const float*)d_in[8];
  const float* b_l1_iu = (const float*)d_in[9];
  const float* W_l2_ui = (const float*)d_in[10];
  const float* W_r2_ui = (const float*)d_in[11];
  const float* b_l2_ui = (const float*)d_in[12];
  const float* W_l2_iu = (const float*)d_in[13];
  const float* W_r2_iu = (const float*)d_in[14];
  const float* b_l2_iu = (const float*)d_in[15];

  const int NU = in_sizes[0] / 128;   // 200000
  const int NI = in_sizes[1] / 128;   // 100000
  const int E  = in_sizes[2];         // 500000
  const int NA = NI + NU;

  char* ws = (char*)d_ws;
  size_t off = 0;
  auto alloc = [&](size_t bytes) -> void* {
    void* p = ws + off;
    off += (bytes + 255) & ~(size_t)255;
    return p;
  };

  // --- zeroed-every-launch region ---
  int* cntAll = (int*)alloc((size_t)NA * 4);
  int* curAll = (int*)alloc((size_t)NA * 4);
  size_t zeroBytes = off;
  // --- CSR ---
  int* offAll   = (int*)alloc((size_t)(NA + 1) * 4);
  int* tileSums = (int*)alloc(256 * 4);
  int* idxAll   = (int*)alloc((size_t)2 * E * 4);
  // --- weights (bf16, transposed) ---
  unsigned short* WT1_ui  = (unsigned short*)alloc(256 * 256 * 2);
  unsigned short* WT1_iu  = (unsigned short*)alloc(256 * 256 * 2);
  unsigned short* WT2l_ui = (unsigned short*)alloc(128 * 256 * 2);
  unsigned short* WT2r_ui = (unsigned short*)alloc(128 * 256 * 2);
  unsigned short* WT2l_iu = (unsigned short*)alloc(128 * 256 * 2);
  unsigned short* WT2r_iu = (unsigned short*)alloc(128 * 256 * 2);
  // --- hidden states ---
  unsigned short* h_item = (unsigned short*)alloc((size_t)NI * 256 * 2);
  unsigned short* h_user = (unsigned short*)alloc((size_t)NU * 256 * 2);
  // --- time-shared region R (153.6 MB) ---
  char* R = (char*)alloc((size_t)NA * 256 * 2);
  // layer-1 phase:
  unsigned int* Acat_item = (unsigned int*)R;                                     // NI*128 uint
  unsigned int* Acat_user = (unsigned int*)(R + (size_t)NI * 256 * 2);            // NU*128 uint
  // layer-2 phase (Acat dead after L1 GEMMs):
  unsigned short* p_user = (unsigned short*)R;                                    // NU*128 bf16
  unsigned short* p_item = (unsigned short*)(R + (size_t)NU * 128 * 2);           // NI*128 bf16
  unsigned short* m2I    = (unsigned short*)(R + (size_t)(NU + NI) * 128 * 2);    // NI*128 bf16
  unsigned short* m2U    = (unsigned short*)(R + (size_t)(NU + 2 * NI) * 128 * 2);// NU*128 bf16

  float* out = (float*)d_out;   // [o_user (NU*128) | o_item (NI*128)] fp32

  // 1) zero counts/cursors
  hipMemsetAsync(ws, 0, zeroBytes, stream);

  // 2) weight transposes (single launch)
  build_wt_all<<<1024, 256, 0, stream>>>(
      W_l1_ui, W_r1_ui, W_l1_iu, W_r1_iu, W_l2_ui, W_r2_ui, W_l2_iu, W_r2_iu,
      WT1_ui, WT1_iu, WT2l_ui, WT2r_ui, WT2l_iu, WT2r_iu);

  // 3) CSR build: hist -> 3-pass scan -> fill
  int egrid = (E + 255) / 256;
  int nTiles = (NA + SCAN_TILE - 1) / SCAN_TILE;
  hist<<<egrid, 256, 0, stream>>>(esrc, edst, cntAll, NI, E);
  scan_p1<<<nTiles, 256, 0, stream>>>(cntAll, tileSums, NA);
  scan_p2<<<1, 256, 0, stream>>>(tileSums, nTiles, offAll + NA);
  scan_p3<<<nTiles, 256, 0, stream>>>(cntAll, tileSums, offAll, NA);
  fill_idx<<<egrid, 256, 0, stream>>>(esrc, edst, offAll, curAll, idxAll, NI, E);

  // 4) layer-1 aggregation -> Acat = [mean | x] bf16 (one launch, both types)
  build_acat<<<(NA * 64 + 255) / 256, 256, 0, stream>>>(
      x_user, x_item, idxAll, offAll, Acat_item, Acat_user, NI, NA);

  // 5) layer-1 GEMMs: h = relu(Acat @ [W_l; W_r] + b), bf16 out
  dim3 gI((NI + 127) / 128, 2), gU((NU + 127) / 128, 2);
  gemm_k256<<<gI, 256, 0, stream>>>((const unsigned short*)Acat_item, WT1_ui, b_l1_ui,
                                    nullptr, h_item, 0, NI, 256, 1);
  gemm_k256<<<gU, 256, 0, stream>>>((const unsigned short*)Acat_user, WT1_iu, b_l1_iu,
                                    nullptr, h_user, 0, NU, 256, 1);

  // 6) layer-2 left-projections: p = h @ W_l2, bf16
  dim3 pGu((NU + 127) / 128, 1), pGi((NI + 127) / 128, 1);
  gemm_k256<<<pGu, 256, 0, stream>>>(h_user, WT2l_ui, nullptr, nullptr, p_user, 0, NU, 128, 0);
  gemm_k256<<<pGi, 256, 0, stream>>>(h_item, WT2l_iu, nullptr, nullptr, p_item, 0, NI, 128, 0);

  // 7) layer-2 aggregation (one launch, both types)
  seg_mean<<<(NA * 64 + 255) / 256, 256, 0, stream>>>(
      (const unsigned int*)p_user, (const unsigned int*)p_item,
      idxAll, offAll, (unsigned int*)m2I, (unsigned int*)m2U, NI, NA);

  // 8) output GEMMs: o = relu(h @ W_r2 + m2 + b), fp32 out
  gemm_k256<<<pGi, 256, 0, stream>>>(h_item, WT2r_ui, b_l2_ui, m2I,
                                     out + (size_t)NU * 128, 1, NI, 128, 1);
  gemm_k256<<<pGu, 256, 0, stream>>>(h_user, WT2r_iu, b_l2_iu, m2U,
                                     out, 1, NU, 128, 1);
}